// Round 1
// baseline (969.053 us; speedup 1.0000x reference)
//
#include <hip/hip_runtime.h>

#define NN 50000
#define NE 800000
#define DD 128

static constexpr unsigned ENC_NEG_INF = 0x007FFFFFu;  // encoded -inf

// Monotone float->uint encoding: order-preserving under unsigned compare.
__device__ __forceinline__ unsigned enc_f(float f) {
    unsigned u = __float_as_uint(f);
    return (u & 0x80000000u) ? ~u : (u | 0x80000000u);
}
__device__ __forceinline__ float dec_f(unsigned e) {
    unsigned u = (e & 0x80000000u) ? (e & 0x7FFFFFFFu) : ~e;
    return __uint_as_float(u);
}

__global__ void fill_kernel(unsigned* __restrict__ p, int n, unsigned v) {
    int i = blockIdx.x * blockDim.x + threadIdx.x;
    if (i < n) p[i] = v;
}

// One half-block (128 threads) per edge: gather x[src], atomic-max into agg[dst].
__global__ __launch_bounds__(256) void scatter_max_kernel(
        const float* __restrict__ x,
        const int* __restrict__ ei,
        unsigned* __restrict__ agg) {
    int e = (blockIdx.x << 1) | (threadIdx.x >> 7);
    int j = threadIdx.x & 127;
    int src = ei[e];
    int dst = ei[NE + e];
    float v = x[(size_t)src * DD + j];
    atomicMax(agg + (size_t)dst * DD + j, enc_f(v));
}

// Fused SAGE layer: xout = relu(agg @ Wl^T + bl + xin @ Wr^T)
// 32 rows per block, 256 threads; thread (j = t&127, rh = t>>7) does 16 rows of col j.
template<bool RELU>
__global__ __launch_bounds__(256) void sage_layer_kernel(
        const float* __restrict__ xin,
        const unsigned* __restrict__ agg,
        const float* __restrict__ Wl,
        const float* __restrict__ bl,
        const float* __restrict__ Wr,
        float* __restrict__ xout) {
    __shared__ float xs[32][DD];
    __shared__ float as[32][DD];
    int row0 = blockIdx.x * 32;
    for (int t = threadIdx.x; t < 32 * DD; t += 256) {
        int r = t >> 7, c = t & 127;
        int row = row0 + r;
        if (row < NN) {
            xs[r][c] = xin[(size_t)row * DD + c];
            unsigned e = agg[(size_t)row * DD + c];
            as[r][c] = (e == ENC_NEG_INF) ? 0.0f : dec_f(e);  // isolated -> 0
        }
    }
    __syncthreads();
    int j = threadIdx.x & 127;
    int rh = threadIdx.x >> 7;
    float acc[16];
    float bj = bl[j];
#pragma unroll
    for (int r = 0; r < 16; r++) acc[r] = bj;
#pragma unroll 4
    for (int k = 0; k < DD; k++) {
        float wl = Wl[j * DD + k];
        float wr = Wr[j * DD + k];
#pragma unroll
        for (int r = 0; r < 16; r++) {
            acc[r] += as[rh * 16 + r][k] * wl + xs[rh * 16 + r][k] * wr;
        }
    }
#pragma unroll
    for (int r = 0; r < 16; r++) {
        int row = row0 + rh * 16 + r;
        if (row < NN) {
            float v = acc[r];
            if (RELU) v = fmaxf(v, 0.0f);
            xout[(size_t)row * DD + j] = v;
        }
    }
}

// out = xin @ W^T + b
__global__ __launch_bounds__(256) void final_gemm_kernel(
        const float* __restrict__ xin,
        const float* __restrict__ W,
        const float* __restrict__ b,
        float* __restrict__ out) {
    __shared__ float xs[32][DD];
    int row0 = blockIdx.x * 32;
    for (int t = threadIdx.x; t < 32 * DD; t += 256) {
        int r = t >> 7, c = t & 127;
        int row = row0 + r;
        if (row < NN) xs[r][c] = xin[(size_t)row * DD + c];
    }
    __syncthreads();
    int j = threadIdx.x & 127;
    int rh = threadIdx.x >> 7;
    float acc[16];
    float bj = b[j];
#pragma unroll
    for (int r = 0; r < 16; r++) acc[r] = bj;
#pragma unroll 4
    for (int k = 0; k < DD; k++) {
        float w = W[j * DD + k];
#pragma unroll
        for (int r = 0; r < 16; r++) {
            acc[r] += xs[rh * 16 + r][k] * w;
        }
    }
#pragma unroll
    for (int r = 0; r < 16; r++) {
        int row = row0 + rh * 16 + r;
        if (row < NN) out[(size_t)row * DD + j] = acc[r];
    }
}

extern "C" void kernel_launch(void* const* d_in, const int* in_sizes, int n_in,
                              void* d_out, int out_size, void* d_ws, size_t ws_size,
                              hipStream_t stream) {
    const float* x  = (const float*)d_in[0];
    const int*   ei = (const int*)d_in[1];   // [2, E] int32
    const float* Wl = (const float*)d_in[2]; // [2, D, D]
    const float* bl = (const float*)d_in[3]; // [2, D]
    const float* Wr = (const float*)d_in[4]; // [2, D, D]
    const float* W  = (const float*)d_in[5]; // [D, D]
    const float* b  = (const float*)d_in[6]; // [D]
    float* out = (float*)d_out;

    unsigned* agg = (unsigned*)d_ws;                       // N*D encoded floats
    float* xbuf   = (float*)d_ws + (size_t)NN * DD;        // N*D floats

    dim3 blk(256);
    int fillBlocks = (NN * DD + 255) / 256;
    int gemmBlocks = (NN + 31) / 32;
    int scatBlocks = NE / 2;

    // Layer 0
    fill_kernel<<<fillBlocks, blk, 0, stream>>>(agg, NN * DD, ENC_NEG_INF);
    scatter_max_kernel<<<scatBlocks, blk, 0, stream>>>(x, ei, agg);
    sage_layer_kernel<true><<<gemmBlocks, blk, 0, stream>>>(x, agg, Wl, bl, Wr, xbuf);

    // Layer 1
    fill_kernel<<<fillBlocks, blk, 0, stream>>>(agg, NN * DD, ENC_NEG_INF);
    scatter_max_kernel<<<scatBlocks, blk, 0, stream>>>(xbuf, ei, agg);
    sage_layer_kernel<true><<<gemmBlocks, blk, 0, stream>>>(
        xbuf, agg, Wl + DD * DD, bl + DD, Wr + DD * DD, xbuf);

    // Final linear
    final_gemm_kernel<<<gemmBlocks, blk, 0, stream>>>(xbuf, W, b, out);
}

// Round 2
// 590.403 us; speedup vs baseline: 1.6413x; 1.6413x over previous
//
#include <hip/hip_runtime.h>
#include <math.h>

#define NN 50000
#define NE 800000
#define DD 128
#define SCAN_BLOCKS 196  // ceil(NN/256)

__global__ __launch_bounds__(256) void zero_int(int* __restrict__ p, int n) {
    int i = blockIdx.x * 256 + threadIdx.x;
    if (i < n) p[i] = 0;
}

__global__ __launch_bounds__(256) void hist_kernel(const int* __restrict__ ei,
                                                   int* __restrict__ deg) {
    int e = blockIdx.x * 256 + threadIdx.x;
    if (e < NE) atomicAdd(&deg[ei[NE + e]], 1);
}

// Block-level exclusive scan, pass 1: per-256 partials + block sums.
__global__ __launch_bounds__(256) void scan_a(const int* __restrict__ deg,
                                              int* __restrict__ partial,
                                              int* __restrict__ bsum) {
    __shared__ int s[256];
    int t = threadIdx.x;
    int i = blockIdx.x * 256 + t;
    int v = (i < NN) ? deg[i] : 0;
    s[t] = v;
    __syncthreads();
    for (int o = 1; o < 256; o <<= 1) {
        int u = (t >= o) ? s[t - o] : 0;
        __syncthreads();
        s[t] += u;
        __syncthreads();
    }
    if (i < NN) partial[i] = s[t] - v;  // exclusive
    if (t == 255) bsum[blockIdx.x] = s[255];
}

// pass 2: scan the block sums (single block; SCAN_BLOCKS <= 256).
__global__ __launch_bounds__(256) void scan_b(int* __restrict__ bsum) {
    __shared__ int s[256];
    int t = threadIdx.x;
    int v = (t < SCAN_BLOCKS) ? bsum[t] : 0;
    s[t] = v;
    __syncthreads();
    for (int o = 1; o < 256; o <<= 1) {
        int u = (t >= o) ? s[t - o] : 0;
        __syncthreads();
        s[t] += u;
        __syncthreads();
    }
    bsum[t] = s[t] - v;  // exclusive
}

// pass 3: add block offsets -> row_ptr; init cursor = row_ptr.
__global__ __launch_bounds__(256) void scan_c(int* __restrict__ row_ptr,
                                              const int* __restrict__ bsum,
                                              int* __restrict__ cursor) {
    int i = blockIdx.x * 256 + threadIdx.x;
    if (i < NN) {
        int v = row_ptr[i] + bsum[blockIdx.x];
        row_ptr[i] = v;
        cursor[i] = v;
    }
    if (i == 0) row_ptr[NN] = NE;
}

__global__ __launch_bounds__(256) void fill_col(const int* __restrict__ ei,
                                                int* __restrict__ cursor,
                                                int* __restrict__ col) {
    int e = blockIdx.x * 256 + threadIdx.x;
    if (e < NE) {
        int src = ei[e];
        int dst = ei[NE + e];
        int p = atomicAdd(&cursor[dst], 1);
        col[p] = src;
    }
}

// Segmented max: 32 lanes per node, float4 per lane (512 B/row coalesced).
__global__ __launch_bounds__(256) void agg_kernel(const float4* __restrict__ x4,
                                                  const int* __restrict__ row_ptr,
                                                  const int* __restrict__ col,
                                                  float4* __restrict__ agg4) {
    int node = blockIdx.x * 8 + (threadIdx.x >> 5);
    if (node >= NN) return;
    int j = threadIdx.x & 31;
    int s0 = row_ptr[node], s1 = row_ptr[node + 1];
    float4 m = make_float4(0.f, 0.f, 0.f, 0.f);  // isolated -> 0
    if (s0 < s1) {
        m = make_float4(-INFINITY, -INFINITY, -INFINITY, -INFINITY);
        for (int i = s0; i < s1; i++) {
            int s = col[i];
            float4 v = x4[(size_t)s * 32 + j];
            m.x = fmaxf(m.x, v.x);
            m.y = fmaxf(m.y, v.y);
            m.z = fmaxf(m.z, v.z);
            m.w = fmaxf(m.w, v.w);
        }
    }
    agg4[(size_t)node * 32 + j] = m;
}

// Fused SAGE layer: xout = relu(agg @ Wl^T + bl + xin @ Wr^T)
// 32 rows/block, 256 threads; in-place-safe (stages own rows via LDS).
template<bool RELU>
__global__ __launch_bounds__(256) void sage_layer_kernel(
        const float* __restrict__ xin,
        const float* __restrict__ agg,
        const float* __restrict__ Wl,
        const float* __restrict__ bl,
        const float* __restrict__ Wr,
        float* __restrict__ xout) {
    __shared__ float xs[32][DD];
    __shared__ float as[32][DD];
    int row0 = blockIdx.x * 32;
    for (int t = threadIdx.x; t < 32 * DD; t += 256) {
        int r = t >> 7, c = t & 127;
        int row = row0 + r;
        if (row < NN) {
            xs[r][c] = xin[(size_t)row * DD + c];
            as[r][c] = agg[(size_t)row * DD + c];
        }
    }
    __syncthreads();
    int j = threadIdx.x & 127;
    int rh = threadIdx.x >> 7;
    float acc[16];
    float bj = bl[j];
#pragma unroll
    for (int r = 0; r < 16; r++) acc[r] = bj;
#pragma unroll 4
    for (int k = 0; k < DD; k++) {
        float wl = Wl[j * DD + k];
        float wr = Wr[j * DD + k];
#pragma unroll
        for (int r = 0; r < 16; r++) {
            acc[r] += as[rh * 16 + r][k] * wl + xs[rh * 16 + r][k] * wr;
        }
    }
#pragma unroll
    for (int r = 0; r < 16; r++) {
        int row = row0 + rh * 16 + r;
        if (row < NN) {
            float v = acc[r];
            if (RELU) v = fmaxf(v, 0.0f);
            xout[(size_t)row * DD + j] = v;
        }
    }
}

// out = xin @ W^T + b (in-place-safe)
__global__ __launch_bounds__(256) void final_gemm_kernel(
        const float* __restrict__ xin,
        const float* __restrict__ W,
        const float* __restrict__ b,
        float* __restrict__ out) {
    __shared__ float xs[32][DD];
    int row0 = blockIdx.x * 32;
    for (int t = threadIdx.x; t < 32 * DD; t += 256) {
        int r = t >> 7, c = t & 127;
        int row = row0 + r;
        if (row < NN) xs[r][c] = xin[(size_t)row * DD + c];
    }
    __syncthreads();
    int j = threadIdx.x & 127;
    int rh = threadIdx.x >> 7;
    float acc[16];
    float bj = b[j];
#pragma unroll
    for (int r = 0; r < 16; r++) acc[r] = bj;
#pragma unroll 4
    for (int k = 0; k < DD; k++) {
        float w = W[j * DD + k];
#pragma unroll
        for (int r = 0; r < 16; r++) {
            acc[r] += xs[rh * 16 + r][k] * w;
        }
    }
#pragma unroll
    for (int r = 0; r < 16; r++) {
        int row = row0 + rh * 16 + r;
        if (row < NN) out[(size_t)row * DD + j] = acc[r];
    }
}

extern "C" void kernel_launch(void* const* d_in, const int* in_sizes, int n_in,
                              void* d_out, int out_size, void* d_ws, size_t ws_size,
                              hipStream_t stream) {
    const float* x  = (const float*)d_in[0];
    const int*   ei = (const int*)d_in[1];   // [2, E]
    const float* Wl = (const float*)d_in[2]; // [2, D, D]
    const float* bl = (const float*)d_in[3]; // [2, D]
    const float* Wr = (const float*)d_in[4]; // [2, D, D]
    const float* W  = (const float*)d_in[5]; // [D, D]
    const float* b  = (const float*)d_in[6]; // [D]
    float* out = (float*)d_out;

    // workspace layout (~29.2 MB)
    float* agg    = (float*)d_ws;                 // N*D floats
    int*   col    = (int*)(agg + (size_t)NN * DD); // E ints
    int*   rowptr = col + NE;                      // N+1 ints
    int*   deg    = rowptr + NN + 1;               // N ints (reused as cursor)
    int*   bsum   = deg + NN;                      // 256 ints

    dim3 blk(256);
    int edgeBlocks = (NE + 255) / 256;   // 3125
    int gemmBlocks = (NN + 31) / 32;     // 1563
    int aggBlocks  = (NN + 7) / 8;       // 6250

    // --- CSR build (once; reused by both layers) ---
    zero_int<<<SCAN_BLOCKS, blk, 0, stream>>>(deg, NN);
    hist_kernel<<<edgeBlocks, blk, 0, stream>>>(ei, deg);
    scan_a<<<SCAN_BLOCKS, blk, 0, stream>>>(deg, rowptr, bsum);
    scan_b<<<1, blk, 0, stream>>>(bsum);
    scan_c<<<SCAN_BLOCKS, blk, 0, stream>>>(rowptr, bsum, deg /*cursor*/);
    fill_col<<<edgeBlocks, blk, 0, stream>>>(ei, deg /*cursor*/, col);

    // --- Layer 0 ---
    agg_kernel<<<aggBlocks, blk, 0, stream>>>((const float4*)x, rowptr, col, (float4*)agg);
    sage_layer_kernel<true><<<gemmBlocks, blk, 0, stream>>>(x, agg, Wl, bl, Wr, out);

    // --- Layer 1 (in-place on out) ---
    agg_kernel<<<aggBlocks, blk, 0, stream>>>((const float4*)out, rowptr, col, (float4*)agg);
    sage_layer_kernel<true><<<gemmBlocks, blk, 0, stream>>>(
        out, agg, Wl + DD * DD, bl + DD, Wr + DD * DD, out);

    // --- Final linear (in-place) ---
    final_gemm_kernel<<<gemmBlocks, blk, 0, stream>>>(out, W, b, out);
}

// Round 3
// 424.084 us; speedup vs baseline: 2.2851x; 1.3922x over previous
//
#include <hip/hip_runtime.h>
#include <math.h>

#define NN 50000
#define NE 800000
#define DD 128
#define SCAN_BLOCKS 196  // ceil(NN/256)

// ---------------- CSR build ----------------
__global__ __launch_bounds__(256) void zero_int(int* __restrict__ p, int n) {
    int i = blockIdx.x * 256 + threadIdx.x;
    if (i < n) p[i] = 0;
}

__global__ __launch_bounds__(256) void hist_kernel(const int* __restrict__ ei,
                                                   int* __restrict__ deg) {
    int e = blockIdx.x * 256 + threadIdx.x;
    if (e < NE) atomicAdd(&deg[ei[NE + e]], 1);
}

__global__ __launch_bounds__(256) void scan_a(const int* __restrict__ deg,
                                              int* __restrict__ partial,
                                              int* __restrict__ bsum) {
    __shared__ int s[256];
    int t = threadIdx.x;
    int i = blockIdx.x * 256 + t;
    int v = (i < NN) ? deg[i] : 0;
    s[t] = v;
    __syncthreads();
    for (int o = 1; o < 256; o <<= 1) {
        int u = (t >= o) ? s[t - o] : 0;
        __syncthreads();
        s[t] += u;
        __syncthreads();
    }
    if (i < NN) partial[i] = s[t] - v;
    if (t == 255) bsum[blockIdx.x] = s[255];
}

__global__ __launch_bounds__(256) void scan_b(int* __restrict__ bsum) {
    __shared__ int s[256];
    int t = threadIdx.x;
    int v = (t < SCAN_BLOCKS) ? bsum[t] : 0;
    s[t] = v;
    __syncthreads();
    for (int o = 1; o < 256; o <<= 1) {
        int u = (t >= o) ? s[t - o] : 0;
        __syncthreads();
        s[t] += u;
        __syncthreads();
    }
    bsum[t] = s[t] - v;
}

__global__ __launch_bounds__(256) void scan_c(int* __restrict__ row_ptr,
                                              const int* __restrict__ bsum,
                                              int* __restrict__ cursor) {
    int i = blockIdx.x * 256 + threadIdx.x;
    if (i < NN) {
        int v = row_ptr[i] + bsum[blockIdx.x];
        row_ptr[i] = v;
        cursor[i] = v;
    }
    if (i == 0) row_ptr[NN] = NE;
}

__global__ __launch_bounds__(256) void fill_col(const int* __restrict__ ei,
                                                int* __restrict__ cursor,
                                                int* __restrict__ col) {
    int e = blockIdx.x * 256 + threadIdx.x;
    if (e < NE) {
        int src = ei[e];
        int dst = ei[NE + e];
        int p = atomicAdd(&cursor[dst], 1);
        col[p] = src;
    }
}

// ---------------- weight transpose: WT[k][j] = (k<DD ? Wl[j][k] : Wr[j][k-DD]) ----------------
__global__ __launch_bounds__(256) void transpose_weights(const float* __restrict__ Wl,
                                                         const float* __restrict__ Wr,
                                                         float* __restrict__ WT, int ktot) {
    int idx = blockIdx.x * 256 + threadIdx.x;
    if (idx >= ktot * DD) return;
    int k = idx / DD, j = idx % DD;
    WT[idx] = (k < DD) ? Wl[j * DD + k] : Wr[j * DD + (k - DD)];
}

// ---------------- segmented max (CSR), 32 lanes/node, unroll-4 ----------------
__global__ __launch_bounds__(256) void agg_kernel(const float4* __restrict__ x4,
                                                  const int* __restrict__ row_ptr,
                                                  const int* __restrict__ col,
                                                  float4* __restrict__ agg4) {
    int node = blockIdx.x * 8 + (threadIdx.x >> 5);
    if (node >= NN) return;
    int j = threadIdx.x & 31;
    int s0 = row_ptr[node], s1 = row_ptr[node + 1];
    if (s0 == s1) {
        agg4[(size_t)node * 32 + j] = make_float4(0.f, 0.f, 0.f, 0.f);
        return;
    }
    float4 m0 = make_float4(-INFINITY, -INFINITY, -INFINITY, -INFINITY);
    float4 m1 = m0, m2 = m0, m3 = m0;
    int i = s0;
    for (; i + 4 <= s1; i += 4) {
        int c0 = col[i], c1 = col[i + 1], c2 = col[i + 2], c3 = col[i + 3];
        float4 v0 = x4[(size_t)c0 * 32 + j];
        float4 v1 = x4[(size_t)c1 * 32 + j];
        float4 v2 = x4[(size_t)c2 * 32 + j];
        float4 v3 = x4[(size_t)c3 * 32 + j];
        m0.x = fmaxf(m0.x, v0.x); m0.y = fmaxf(m0.y, v0.y); m0.z = fmaxf(m0.z, v0.z); m0.w = fmaxf(m0.w, v0.w);
        m1.x = fmaxf(m1.x, v1.x); m1.y = fmaxf(m1.y, v1.y); m1.z = fmaxf(m1.z, v1.z); m1.w = fmaxf(m1.w, v1.w);
        m2.x = fmaxf(m2.x, v2.x); m2.y = fmaxf(m2.y, v2.y); m2.z = fmaxf(m2.z, v2.z); m2.w = fmaxf(m2.w, v2.w);
        m3.x = fmaxf(m3.x, v3.x); m3.y = fmaxf(m3.y, v3.y); m3.z = fmaxf(m3.z, v3.z); m3.w = fmaxf(m3.w, v3.w);
    }
    for (; i < s1; i++) {
        float4 v = x4[(size_t)col[i] * 32 + j];
        m0.x = fmaxf(m0.x, v.x); m0.y = fmaxf(m0.y, v.y); m0.z = fmaxf(m0.z, v.z); m0.w = fmaxf(m0.w, v.w);
    }
    m0.x = fmaxf(fmaxf(m0.x, m1.x), fmaxf(m2.x, m3.x));
    m0.y = fmaxf(fmaxf(m0.y, m1.y), fmaxf(m2.y, m3.y));
    m0.z = fmaxf(fmaxf(m0.z, m1.z), fmaxf(m2.z, m3.z));
    m0.w = fmaxf(fmaxf(m0.w, m1.w), fmaxf(m2.w, m3.w));
    agg4[(size_t)node * 32 + j] = m0;
}

// ---------------- register-tiled GEMM ----------------
// out[row][j] = bias[j] + sum_k in[row][k] * WT[k][j], in = [srcA | srcB] (k = 256) or srcA (k = 128)
// tile: 128 rows x 128 cols per block; 256 threads; thread = 8 rows x 8 cols.
// ins[128][65]: pad 65 -> broadcast reads ins[8ty+i][k] land in distinct banks (8*65%32=8).
template<bool HAS_B, bool RELU>
__global__ __launch_bounds__(256) void gemm_kernel(const float4* __restrict__ srcA,
                                                   const float4* __restrict__ srcB,
                                                   const float4* __restrict__ WT4,
                                                   const float* __restrict__ bias,
                                                   float* __restrict__ out) {
    __shared__ float ins[128][65];
    __shared__ float wt[64][DD];
    int tid = threadIdx.x;
    int tx = tid & 15, ty = tid >> 4;
    int row0 = blockIdx.x * 128;

    float acc[8][8];
    {
        float4 b0 = ((const float4*)bias)[2 * tx];
        float4 b1 = ((const float4*)bias)[2 * tx + 1];
#pragma unroll
        for (int i = 0; i < 8; i++) {
            acc[i][0] = b0.x; acc[i][1] = b0.y; acc[i][2] = b0.z; acc[i][3] = b0.w;
            acc[i][4] = b1.x; acc[i][5] = b1.y; acc[i][6] = b1.z; acc[i][7] = b1.w;
        }
    }

    const int nch = HAS_B ? 4 : 2;
    for (int c = 0; c < nch; c++) {
        const float4* src = (HAS_B && c >= 2) ? srcB : srcA;
        int koff4 = (c & 1) * 16;
        // stage inputs: 128 rows x 16 float4
#pragma unroll
        for (int i = 0; i < 8; i++) {
            int idx = tid + 256 * i;
            int r = idx >> 4, c4 = idx & 15;
            int row = row0 + r;
            float4 v = make_float4(0.f, 0.f, 0.f, 0.f);
            if (row < NN) v = src[(size_t)row * 32 + koff4 + c4];
            ins[r][4 * c4 + 0] = v.x;
            ins[r][4 * c4 + 1] = v.y;
            ins[r][4 * c4 + 2] = v.z;
            ins[r][4 * c4 + 3] = v.w;
        }
        // stage weights: 64 k x 32 float4
#pragma unroll
        for (int i = 0; i < 8; i++) {
            int idx = tid + 256 * i;
            int k = idx >> 5, j4 = idx & 31;
            float4 w = WT4[(size_t)(c * 64 + k) * 32 + j4];
            *(float4*)&wt[k][4 * j4] = w;
        }
        __syncthreads();
#pragma unroll 2
        for (int k = 0; k < 64; k++) {
            float a[8], w[8];
#pragma unroll
            for (int i = 0; i < 8; i++) a[i] = ins[8 * ty + i][k];
            *(float4*)&w[0] = *(const float4*)&wt[k][8 * tx];
            *(float4*)&w[4] = *(const float4*)&wt[k][8 * tx + 4];
#pragma unroll
            for (int i = 0; i < 8; i++)
#pragma unroll
                for (int q = 0; q < 8; q++) acc[i][q] += a[i] * w[q];
        }
        __syncthreads();
    }

#pragma unroll
    for (int i = 0; i < 8; i++) {
        int row = row0 + 8 * ty + i;
        if (row < NN) {
            float4 v0, v1;
            v0.x = acc[i][0]; v0.y = acc[i][1]; v0.z = acc[i][2]; v0.w = acc[i][3];
            v1.x = acc[i][4]; v1.y = acc[i][5]; v1.z = acc[i][6]; v1.w = acc[i][7];
            if (RELU) {
                v0.x = fmaxf(v0.x, 0.f); v0.y = fmaxf(v0.y, 0.f); v0.z = fmaxf(v0.z, 0.f); v0.w = fmaxf(v0.w, 0.f);
                v1.x = fmaxf(v1.x, 0.f); v1.y = fmaxf(v1.y, 0.f); v1.z = fmaxf(v1.z, 0.f); v1.w = fmaxf(v1.w, 0.f);
            }
            *(float4*)&out[(size_t)row * DD + 8 * tx] = v0;
            *(float4*)&out[(size_t)row * DD + 8 * tx + 4] = v1;
        }
    }
}

extern "C" void kernel_launch(void* const* d_in, const int* in_sizes, int n_in,
                              void* d_out, int out_size, void* d_ws, size_t ws_size,
                              hipStream_t stream) {
    const float* x  = (const float*)d_in[0];
    const int*   ei = (const int*)d_in[1];
    const float* Wl = (const float*)d_in[2];
    const float* bl = (const float*)d_in[3];
    const float* Wr = (const float*)d_in[4];
    const float* W  = (const float*)d_in[5];
    const float* b  = (const float*)d_in[6];
    float* out = (float*)d_out;

    // ws layout: float4-aligned arrays first
    float* agg    = (float*)d_ws;                       // NN*DD
    float* WT0    = agg + (size_t)NN * DD;              // 256*128
    float* WT1    = WT0 + 2 * DD * DD;                  // 256*128
    float* WTf    = WT1 + 2 * DD * DD;                  // 128*128
    int*   col    = (int*)(WTf + DD * DD);              // NE
    int*   rowptr = col + NE;                           // NN+1
    int*   deg    = rowptr + NN + 1;                    // NN (cursor)
    int*   bsum   = deg + NN;                           // 256

    dim3 blk(256);
    int edgeBlocks = (NE + 255) / 256;
    int gemmBlocks = (NN + 127) / 128;   // 391
    int aggBlocks  = (NN + 7) / 8;
    int twBlocks   = (2 * DD * DD + 255) / 256;
    int twBlocksF  = (DD * DD + 255) / 256;

    // CSR build (edge_index identical for both layers)
    zero_int<<<SCAN_BLOCKS, blk, 0, stream>>>(deg, NN);
    hist_kernel<<<edgeBlocks, blk, 0, stream>>>(ei, deg);
    scan_a<<<SCAN_BLOCKS, blk, 0, stream>>>(deg, rowptr, bsum);
    scan_b<<<1, blk, 0, stream>>>(bsum);
    scan_c<<<SCAN_BLOCKS, blk, 0, stream>>>(rowptr, bsum, deg);
    fill_col<<<edgeBlocks, blk, 0, stream>>>(ei, deg, col);

    // weight transposes
    transpose_weights<<<twBlocks, blk, 0, stream>>>(Wl, Wr, WT0, 2 * DD);
    transpose_weights<<<twBlocks, blk, 0, stream>>>(Wl + DD * DD, Wr + DD * DD, WT1, 2 * DD);
    transpose_weights<<<twBlocksF, blk, 0, stream>>>(W, W, WTf, DD);

    // Layer 0
    agg_kernel<<<aggBlocks, blk, 0, stream>>>((const float4*)x, rowptr, col, (float4*)agg);
    gemm_kernel<true, true><<<gemmBlocks, blk, 0, stream>>>(
        (const float4*)agg, (const float4*)x, (const float4*)WT0, bl, out);

    // Layer 1 (in-place on out: each block stages its own rows before writing)
    agg_kernel<<<aggBlocks, blk, 0, stream>>>((const float4*)out, rowptr, col, (float4*)agg);
    gemm_kernel<true, true><<<gemmBlocks, blk, 0, stream>>>(
        (const float4*)agg, (const float4*)out, (const float4*)WT1, bl + DD, out);

    // Final linear (in-place)
    gemm_kernel<false, false><<<gemmBlocks, blk, 0, stream>>>(
        (const float4*)out, nullptr, (const float4*)WTf, b, out);
}

// Round 4
// 303.186 us; speedup vs baseline: 3.1962x; 1.3988x over previous
//
#include <hip/hip_runtime.h>
#include <math.h>

#define NN 50000
#define NE 800000
#define DD 128
#define SCAN_BLOCKS 196  // ceil(NN/256)

typedef unsigned short u16;
typedef short s8v __attribute__((ext_vector_type(8)));    // 8 bf16 (4 VGPRs)
typedef float f16v __attribute__((ext_vector_type(16)));  // 16 fp32 acc

__device__ __forceinline__ u16 f2bf(float f) {  // RNE fp32->bf16
    unsigned u = __float_as_uint(f);
    return (u16)((u + 0x7FFFu + ((u >> 16) & 1u)) >> 16);
}
__device__ __forceinline__ float bf2f(u16 h) {
    return __uint_as_float(((unsigned)h) << 16);
}

// ---------------- CSR build ----------------
__global__ __launch_bounds__(256) void zero_int(int* __restrict__ p, int n) {
    int i = blockIdx.x * 256 + threadIdx.x;
    if (i < n) p[i] = 0;
}

__global__ __launch_bounds__(256) void hist_kernel(const int* __restrict__ ei,
                                                   int* __restrict__ deg) {
    int e = blockIdx.x * 256 + threadIdx.x;
    if (e < NE) atomicAdd(&deg[ei[NE + e]], 1);
}

__global__ __launch_bounds__(256) void scan_a(const int* __restrict__ deg,
                                              int* __restrict__ partial,
                                              int* __restrict__ bsum) {
    __shared__ int s[256];
    int t = threadIdx.x;
    int i = blockIdx.x * 256 + t;
    int v = (i < NN) ? deg[i] : 0;
    s[t] = v;
    __syncthreads();
    for (int o = 1; o < 256; o <<= 1) {
        int u = (t >= o) ? s[t - o] : 0;
        __syncthreads();
        s[t] += u;
        __syncthreads();
    }
    if (i < NN) partial[i] = s[t] - v;
    if (t == 255) bsum[blockIdx.x] = s[255];
}

__global__ __launch_bounds__(256) void scan_b(int* __restrict__ bsum) {
    __shared__ int s[256];
    int t = threadIdx.x;
    int v = (t < SCAN_BLOCKS) ? bsum[t] : 0;
    s[t] = v;
    __syncthreads();
    for (int o = 1; o < 256; o <<= 1) {
        int u = (t >= o) ? s[t - o] : 0;
        __syncthreads();
        s[t] += u;
        __syncthreads();
    }
    bsum[t] = s[t] - v;
}

__global__ __launch_bounds__(256) void scan_c(int* __restrict__ row_ptr,
                                              const int* __restrict__ bsum,
                                              int* __restrict__ cursor) {
    int i = blockIdx.x * 256 + threadIdx.x;
    if (i < NN) {
        int v = row_ptr[i] + bsum[blockIdx.x];
        row_ptr[i] = v;
        cursor[i] = v;
    }
    if (i == 0) row_ptr[NN] = NE;
}

__global__ __launch_bounds__(256) void fill_col(const int* __restrict__ ei,
                                                int* __restrict__ cursor,
                                                int* __restrict__ col) {
    int e = blockIdx.x * 256 + threadIdx.x;
    if (e < NE) {
        int src = ei[e];
        int dst = ei[NE + e];
        int p = atomicAdd(&cursor[dst], 1);
        col[p] = src;
    }
}

// ---------------- fp32 -> bf16 convert ----------------
__global__ __launch_bounds__(256) void conv_bf16(const float4* __restrict__ in,
                                                 ushort4* __restrict__ out, int n4) {
    int i = blockIdx.x * 256 + threadIdx.x;
    if (i >= n4) return;
    float4 v = in[i];
    ushort4 o;
    o.x = f2bf(v.x); o.y = f2bf(v.y); o.z = f2bf(v.z); o.w = f2bf(v.w);
    out[i] = o;
}

// ---------------- weight pack: B-fragment order for 32x32x16 bf16 MFMA ----------------
// out[((c*4+n)*64+l)*8+j] = Wcat[col = n*32+(l&31)][k = c*16+(l>>5)*8+j]
template<int NKC16, bool TWO>
__global__ __launch_bounds__(256) void pack_weights(const float* __restrict__ Wl,
                                                    const float* __restrict__ Wr,
                                                    u16* __restrict__ out) {
    int o = blockIdx.x * 256 + threadIdx.x;
    if (o >= NKC16 * 2048) return;
    int j = o & 7;
    int l = (o >> 3) & 63;
    int cn = o >> 9;
    int n = cn & 3;
    int c = cn >> 2;
    int col = n * 32 + (l & 31);
    int k = c * 16 + (l >> 5) * 8 + j;
    float v;
    if (TWO) v = (k < DD) ? Wl[col * DD + k] : Wr[col * DD + (k - DD)];
    else     v = Wl[col * DD + k];
    out[o] = f2bf(v);
}

// ---------------- segmented max on bf16 (CSR), 32 lanes/node ----------------
__global__ __launch_bounds__(256) void agg_kernel_bf(const u16* __restrict__ xb,
                                                     const int* __restrict__ row_ptr,
                                                     const int* __restrict__ col,
                                                     u16* __restrict__ aggb) {
    int node = blockIdx.x * 8 + (threadIdx.x >> 5);
    if (node >= NN) return;
    int j = threadIdx.x & 31;
    u16* outp = aggb + (size_t)node * DD + j * 4;
    int s0 = row_ptr[node], s1 = row_ptr[node + 1];
    if (s0 == s1) {
        ushort4 z; z.x = z.y = z.z = z.w = 0;
        *(ushort4*)outp = z;
        return;
    }
    float m0[4], m1[4], m2[4], m3[4];
#pragma unroll
    for (int q = 0; q < 4; q++) { m0[q] = m1[q] = m2[q] = m3[q] = -INFINITY; }
    int i = s0;
    for (; i + 4 <= s1; i += 4) {
        int c0 = col[i], c1 = col[i + 1], c2 = col[i + 2], c3 = col[i + 3];
        ushort4 v0 = *(const ushort4*)(xb + (size_t)c0 * DD + j * 4);
        ushort4 v1 = *(const ushort4*)(xb + (size_t)c1 * DD + j * 4);
        ushort4 v2 = *(const ushort4*)(xb + (size_t)c2 * DD + j * 4);
        ushort4 v3 = *(const ushort4*)(xb + (size_t)c3 * DD + j * 4);
        m0[0] = fmaxf(m0[0], bf2f(v0.x)); m0[1] = fmaxf(m0[1], bf2f(v0.y));
        m0[2] = fmaxf(m0[2], bf2f(v0.z)); m0[3] = fmaxf(m0[3], bf2f(v0.w));
        m1[0] = fmaxf(m1[0], bf2f(v1.x)); m1[1] = fmaxf(m1[1], bf2f(v1.y));
        m1[2] = fmaxf(m1[2], bf2f(v1.z)); m1[3] = fmaxf(m1[3], bf2f(v1.w));
        m2[0] = fmaxf(m2[0], bf2f(v2.x)); m2[1] = fmaxf(m2[1], bf2f(v2.y));
        m2[2] = fmaxf(m2[2], bf2f(v2.z)); m2[3] = fmaxf(m2[3], bf2f(v2.w));
        m3[0] = fmaxf(m3[0], bf2f(v3.x)); m3[1] = fmaxf(m3[1], bf2f(v3.y));
        m3[2] = fmaxf(m3[2], bf2f(v3.z)); m3[3] = fmaxf(m3[3], bf2f(v3.w));
    }
    for (; i < s1; i++) {
        ushort4 v = *(const ushort4*)(xb + (size_t)col[i] * DD + j * 4);
        m0[0] = fmaxf(m0[0], bf2f(v.x)); m0[1] = fmaxf(m0[1], bf2f(v.y));
        m0[2] = fmaxf(m0[2], bf2f(v.z)); m0[3] = fmaxf(m0[3], bf2f(v.w));
    }
#pragma unroll
    for (int q = 0; q < 4; q++) m0[q] = fmaxf(fmaxf(m0[q], m1[q]), fmaxf(m2[q], m3[q]));
    ushort4 o;  // values are exact bf16 -> truncation is exact
    o.x = (u16)(__float_as_uint(m0[0]) >> 16);
    o.y = (u16)(__float_as_uint(m0[1]) >> 16);
    o.z = (u16)(__float_as_uint(m0[2]) >> 16);
    o.w = (u16)(__float_as_uint(m0[3]) >> 16);
    *(ushort4*)outp = o;
}

// ---------------- MFMA GEMM ----------------
// out[row][col] = bias[col] + sum_k A[row][k] * Wcat[col][k]
// A = [srcA | srcB] (TWO_SRC, K=256) or srcA (K=128). 128 rows x 128 cols / block.
// 4 waves; wave wt handles rows wt*32..+31, all 128 cols (4 col-tiles of 32).
template<int NKC16, bool TWO_SRC, bool RELU, bool OUT_BF16>
__global__ __launch_bounds__(256) void mfma_gemm(const u16* __restrict__ srcA,
                                                 const u16* __restrict__ srcB,
                                                 const u16* __restrict__ Bpk,
                                                 const float* __restrict__ bias,
                                                 void* __restrict__ outv) {
    __shared__ s8v ldsB[NKC16 * 4 * 64];
    int tid = threadIdx.x;
    // stage packed weights -> LDS (coalesced float4 copy)
#pragma unroll
    for (int i = 0; i < NKC16; i++) {
        ((float4*)ldsB)[tid + 256 * i] = ((const float4*)Bpk)[tid + 256 * i];
    }

    int wt = tid >> 6;
    int lane = tid & 63;
    int row0 = blockIdx.x * 128 + wt * 32;
    int rload = row0 + (lane & 31);
    if (rload > NN - 1) rload = NN - 1;  // clamp OOB loads
    int koff = (lane >> 5) * 8;

    f16v acc[4];
#pragma unroll
    for (int n = 0; n < 4; n++) acc[n] = (f16v)(0.0f);

    __syncthreads();

#pragma unroll
    for (int c = 0; c < NKC16; c++) {
        const u16* s = srcA;
        int kk = c * 16;
        if (TWO_SRC && c >= 8) { s = srcB; kk = (c - 8) * 16; }
        s8v a = *(const s8v*)(s + (size_t)rload * DD + kk + koff);
#pragma unroll
        for (int n = 0; n < 4; n++) {
            s8v b = ldsB[(c * 4 + n) * 64 + lane];
            acc[n] = __builtin_amdgcn_mfma_f32_32x32x16_bf16(a, b, acc[n], 0, 0, 0);
        }
    }

    // epilogue: C/D layout col=lane&31, row=(reg&3)+8*(reg>>2)+4*(lane>>5)
    int rowadd = 4 * (lane >> 5);
#pragma unroll
    for (int n = 0; n < 4; n++) {
        int colj = n * 32 + (lane & 31);
        float bj = bias[colj];
#pragma unroll
        for (int r = 0; r < 16; r++) {
            int row = row0 + (r & 3) + 8 * (r >> 2) + rowadd;
            if (row < NN) {
                float v = acc[n][r] + bj;
                if (RELU) v = fmaxf(v, 0.0f);
                if (OUT_BF16) ((u16*)outv)[(size_t)row * DD + colj] = f2bf(v);
                else          ((float*)outv)[(size_t)row * DD + colj] = v;
            }
        }
    }
}

extern "C" void kernel_launch(void* const* d_in, const int* in_sizes, int n_in,
                              void* d_out, int out_size, void* d_ws, size_t ws_size,
                              hipStream_t stream) {
    const float* x  = (const float*)d_in[0];
    const int*   ei = (const int*)d_in[1];
    const float* Wl = (const float*)d_in[2];
    const float* bl = (const float*)d_in[3];
    const float* Wr = (const float*)d_in[4];
    const float* W  = (const float*)d_in[5];
    const float* b  = (const float*)d_in[6];
    float* out = (float*)d_out;

    // ws layout (16B-aligned chunks): bf16 arrays then ints
    u16* aggb = (u16*)d_ws;                         // NN*DD bf16
    u16* hb0  = aggb + (size_t)NN * DD;             // NN*DD
    u16* hb1  = hb0 + (size_t)NN * DD;              // NN*DD
    u16* Bpk0 = hb1 + (size_t)NN * DD;              // 32768
    u16* Bpk1 = Bpk0 + 32768;                       // 32768
    u16* Bpkf = Bpk1 + 32768;                       // 16384
    int* col  = (int*)(Bpkf + 16384);               // NE
    int* rowptr = col + NE;                         // NN+1
    int* deg  = rowptr + NN + 1;                    // NN (cursor)
    int* bsum = deg + NN;                           // 256

    dim3 blk(256);
    int edgeBlocks = (NE + 255) / 256;
    int gemmBlocks = (NN + 127) / 128;   // 391
    int aggBlocks  = (NN + 7) / 8;       // 6250
    int convBlocks = (NN * DD / 4 + 255) / 256;

    // CSR build (edge_index identical for both layers)
    zero_int<<<SCAN_BLOCKS, blk, 0, stream>>>(deg, NN);
    hist_kernel<<<edgeBlocks, blk, 0, stream>>>(ei, deg);
    scan_a<<<SCAN_BLOCKS, blk, 0, stream>>>(deg, rowptr, bsum);
    scan_b<<<1, blk, 0, stream>>>(bsum);
    scan_c<<<SCAN_BLOCKS, blk, 0, stream>>>(rowptr, bsum, deg);
    fill_col<<<edgeBlocks, blk, 0, stream>>>(ei, deg, col);

    // convert x -> bf16; pack weights into B-fragment order
    conv_bf16<<<convBlocks, blk, 0, stream>>>((const float4*)x, (ushort4*)hb0, NN * DD / 4);
    pack_weights<16, true><<<128, blk, 0, stream>>>(Wl, Wr, Bpk0);
    pack_weights<16, true><<<128, blk, 0, stream>>>(Wl + DD * DD, Wr + DD * DD, Bpk1);
    pack_weights<8, false><<<64, blk, 0, stream>>>(W, nullptr, Bpkf);

    // Layer 0
    agg_kernel_bf<<<aggBlocks, blk, 0, stream>>>(hb0, rowptr, col, aggb);
    mfma_gemm<16, true, true, true><<<gemmBlocks, blk, 0, stream>>>(
        aggb, hb0, Bpk0, bl, hb1);

    // Layer 1
    agg_kernel_bf<<<aggBlocks, blk, 0, stream>>>(hb1, rowptr, col, aggb);
    mfma_gemm<16, true, true, true><<<gemmBlocks, blk, 0, stream>>>(
        aggb, hb1, Bpk1, bl + DD, hb0);

    // Final linear -> fp32 out
    mfma_gemm<8, false, false, false><<<gemmBlocks, blk, 0, stream>>>(
        hb0, nullptr, Bpkf, b, out);
}

// Round 5
// 245.590 us; speedup vs baseline: 3.9458x; 1.2345x over previous
//
#include <hip/hip_runtime.h>
#include <math.h>

#define NN 50000
#define NE 800000
#define DD 128
#define NBUCK 196        // ceil(NN/256) buckets of 256 nodes
#define PTILE 4096       // edges per partition block
#define PBLOCKS 196      // ceil(NE/PTILE)

typedef unsigned short u16;
typedef short s8v __attribute__((ext_vector_type(8)));    // 8 bf16 (4 VGPRs)
typedef float f16v __attribute__((ext_vector_type(16)));  // 16 fp32 acc

__device__ __forceinline__ u16 f2bf(float f) {  // RNE fp32->bf16
    unsigned u = __float_as_uint(f);
    return (u16)((u + 0x7FFFu + ((u >> 16) & 1u)) >> 16);
}
__device__ __forceinline__ float bf2f(u16 h) {
    return __uint_as_float(((unsigned)h) << 16);
}
__device__ __forceinline__ float bflo(unsigned u) { return __uint_as_float(u << 16); }
__device__ __forceinline__ float bfhi(unsigned u) { return __uint_as_float(u & 0xFFFF0000u); }

__global__ __launch_bounds__(256) void zero_int(int* __restrict__ p, int n) {
    int i = blockIdx.x * 256 + threadIdx.x;
    if (i < n) p[i] = 0;
}

// ---- Phase A1: coarse bucket histogram (LDS-local, then 196 global atomics/block) ----
__global__ __launch_bounds__(256) void bucket_hist(const int* __restrict__ ei,
                                                   int* __restrict__ bcnt) {
    __shared__ int h[NBUCK];
    for (int i = threadIdx.x; i < NBUCK; i += 256) h[i] = 0;
    __syncthreads();
    int e0 = blockIdx.x * PTILE;
#pragma unroll
    for (int i = 0; i < 16; i++) {
        int e = e0 + i * 256 + threadIdx.x;
        if (e < NE) atomicAdd(&h[ei[NE + e] >> 8], 1);
    }
    __syncthreads();
    for (int i = threadIdx.x; i < NBUCK; i += 256)
        if (h[i]) atomicAdd(&bcnt[i], h[i]);
}

// ---- Phase A2: scan bucket counts -> bases + cursors ----
__global__ __launch_bounds__(256) void bucket_scan(const int* __restrict__ bcnt,
                                                   int* __restrict__ bbase,
                                                   int* __restrict__ bcur,
                                                   int* __restrict__ rowptr) {
    __shared__ int s[256];
    int t = threadIdx.x;
    int v = (t < NBUCK) ? bcnt[t] : 0;
    s[t] = v;
    __syncthreads();
    for (int o = 1; o < 256; o <<= 1) {
        int u = (t >= o) ? s[t - o] : 0;
        __syncthreads();
        s[t] += u;
        __syncthreads();
    }
    int ex = s[t] - v;
    if (t < NBUCK) { bbase[t] = ex; bcur[t] = ex; }
    if (t == 0) rowptr[NN] = NE;
}

// ---- Phase A3: partition edges into bucket-contiguous packed array ----
// packed entry: src (16 bits) | dstlocal (8 bits) << 16
__global__ __launch_bounds__(256) void bucket_partition(const int* __restrict__ ei,
                                                        int* __restrict__ bcur,
                                                        unsigned* __restrict__ packed) {
    __shared__ int h[NBUCK];
    __shared__ int base[NBUCK];
    int t = threadIdx.x;
    for (int i = t; i < NBUCK; i += 256) h[i] = 0;
    __syncthreads();
    int e0 = blockIdx.x * PTILE;
    int dsts[16], srcs[16];
#pragma unroll
    for (int i = 0; i < 16; i++) {
        int e = e0 + i * 256 + t;
        if (e < NE) {
            dsts[i] = ei[NE + e];
            srcs[i] = ei[e];
            atomicAdd(&h[dsts[i] >> 8], 1);
        } else dsts[i] = -1;
    }
    __syncthreads();
    for (int i = t; i < NBUCK; i += 256) {
        int c = h[i];
        base[i] = c ? atomicAdd(&bcur[i], c) : 0;
    }
    __syncthreads();
    for (int i = t; i < NBUCK; i += 256) h[i] = 0;  // reuse as local cursor
    __syncthreads();
#pragma unroll
    for (int i = 0; i < 16; i++) {
        if (dsts[i] >= 0) {
            int bk = dsts[i] >> 8;
            int r = atomicAdd(&h[bk], 1);
            packed[base[bk] + r] = (unsigned)srcs[i] | ((unsigned)(dsts[i] & 255) << 16);
        }
    }
}

// ---- Phase B: per-bucket counting sort -> rowptr + col (all LDS-local) ----
__global__ __launch_bounds__(256) void bucket_csr(const unsigned* __restrict__ packed,
                                                  const int* __restrict__ bcnt,
                                                  const int* __restrict__ bbase,
                                                  int* __restrict__ rowptr,
                                                  int* __restrict__ col) {
    __shared__ int deg[256];
    __shared__ int off[256];
    int bk = blockIdx.x;
    int cnt = bcnt[bk], base = bbase[bk];
    int t = threadIdx.x;
    deg[t] = 0;
    __syncthreads();
    for (int i = t; i < cnt; i += 256) atomicAdd(&deg[packed[base + i] >> 16], 1);
    __syncthreads();
    int v = deg[t];
    off[t] = v;
    __syncthreads();
    for (int o = 1; o < 256; o <<= 1) {
        int u = (t >= o) ? off[t - o] : 0;
        __syncthreads();
        off[t] += u;
        __syncthreads();
    }
    int ex = off[t] - v;
    int node = (bk << 8) + t;
    if (node < NN) rowptr[node] = base + ex;
    deg[t] = ex;  // reuse as cursor
    __syncthreads();
    for (int i = t; i < cnt; i += 256) {
        unsigned p = packed[base + i];
        int dl = p >> 16;
        int r = atomicAdd(&deg[dl], 1);
        col[base + r] = (int)(p & 0xFFFFu);
    }
}

// ---------------- fp32 -> bf16 convert ----------------
__global__ __launch_bounds__(256) void conv_bf16(const float4* __restrict__ in,
                                                 ushort4* __restrict__ out, int n4) {
    int i = blockIdx.x * 256 + threadIdx.x;
    if (i >= n4) return;
    float4 v = in[i];
    ushort4 o;
    o.x = f2bf(v.x); o.y = f2bf(v.y); o.z = f2bf(v.z); o.w = f2bf(v.w);
    out[i] = o;
}

// ---------------- weight pack: B-fragment order for 32x32x16 bf16 MFMA ----------------
// out[((c*4+n)*64+l)*8+j] = Wcat[col = n*32+(l&31)][k = c*16+(l>>5)*8+j]
template<int NKC16, bool TWO>
__global__ __launch_bounds__(256) void pack_weights(const float* __restrict__ Wl,
                                                    const float* __restrict__ Wr,
                                                    u16* __restrict__ out) {
    int o = blockIdx.x * 256 + threadIdx.x;
    if (o >= NKC16 * 2048) return;
    int j = o & 7;
    int l = (o >> 3) & 63;
    int cn = o >> 9;
    int n = cn & 3;
    int c = cn >> 2;
    int colj = n * 32 + (l & 31);
    int k = c * 16 + (l >> 5) * 8 + j;
    float v;
    if (TWO) v = (k < DD) ? Wl[colj * DD + k] : Wr[colj * DD + (k - DD)];
    else     v = Wl[colj * DD + k];
    out[o] = f2bf(v);
}

// ---------------- segmented max on bf16 (CSR), 16 lanes/node, 16B/lane ----------------
__global__ __launch_bounds__(256) void agg_kernel_bf(const uint4* __restrict__ xb4,
                                                     const int* __restrict__ row_ptr,
                                                     const int* __restrict__ col,
                                                     uint4* __restrict__ aggb4) {
    int node = blockIdx.x * 16 + (threadIdx.x >> 4);
    if (node >= NN) return;
    int j = threadIdx.x & 15;
    int s0 = row_ptr[node], s1 = row_ptr[node + 1];
    if (s0 == s1) {
        aggb4[(size_t)node * 16 + j] = make_uint4(0, 0, 0, 0);
        return;
    }
    float m0[8], m1[8], m2[8], m3[8];
#pragma unroll
    for (int q = 0; q < 8; q++) { m0[q] = m1[q] = m2[q] = m3[q] = -INFINITY; }
    int i = s0;
    for (; i + 4 <= s1; i += 4) {
        int c0 = col[i], c1 = col[i + 1], c2 = col[i + 2], c3 = col[i + 3];
        uint4 v0 = xb4[(size_t)c0 * 16 + j];
        uint4 v1 = xb4[(size_t)c1 * 16 + j];
        uint4 v2 = xb4[(size_t)c2 * 16 + j];
        uint4 v3 = xb4[(size_t)c3 * 16 + j];
        m0[0] = fmaxf(m0[0], bflo(v0.x)); m0[1] = fmaxf(m0[1], bfhi(v0.x));
        m0[2] = fmaxf(m0[2], bflo(v0.y)); m0[3] = fmaxf(m0[3], bfhi(v0.y));
        m0[4] = fmaxf(m0[4], bflo(v0.z)); m0[5] = fmaxf(m0[5], bfhi(v0.z));
        m0[6] = fmaxf(m0[6], bflo(v0.w)); m0[7] = fmaxf(m0[7], bfhi(v0.w));
        m1[0] = fmaxf(m1[0], bflo(v1.x)); m1[1] = fmaxf(m1[1], bfhi(v1.x));
        m1[2] = fmaxf(m1[2], bflo(v1.y)); m1[3] = fmaxf(m1[3], bfhi(v1.y));
        m1[4] = fmaxf(m1[4], bflo(v1.z)); m1[5] = fmaxf(m1[5], bfhi(v1.z));
        m1[6] = fmaxf(m1[6], bflo(v1.w)); m1[7] = fmaxf(m1[7], bfhi(v1.w));
        m2[0] = fmaxf(m2[0], bflo(v2.x)); m2[1] = fmaxf(m2[1], bfhi(v2.x));
        m2[2] = fmaxf(m2[2], bflo(v2.y)); m2[3] = fmaxf(m2[3], bfhi(v2.y));
        m2[4] = fmaxf(m2[4], bflo(v2.z)); m2[5] = fmaxf(m2[5], bfhi(v2.z));
        m2[6] = fmaxf(m2[6], bflo(v2.w)); m2[7] = fmaxf(m2[7], bfhi(v2.w));
        m3[0] = fmaxf(m3[0], bflo(v3.x)); m3[1] = fmaxf(m3[1], bfhi(v3.x));
        m3[2] = fmaxf(m3[2], bflo(v3.y)); m3[3] = fmaxf(m3[3], bfhi(v3.y));
        m3[4] = fmaxf(m3[4], bflo(v3.z)); m3[5] = fmaxf(m3[5], bfhi(v3.z));
        m3[6] = fmaxf(m3[6], bflo(v3.w)); m3[7] = fmaxf(m3[7], bfhi(v3.w));
    }
    for (; i < s1; i++) {
        uint4 v = xb4[(size_t)col[i] * 16 + j];
        m0[0] = fmaxf(m0[0], bflo(v.x)); m0[1] = fmaxf(m0[1], bfhi(v.x));
        m0[2] = fmaxf(m0[2], bflo(v.y)); m0[3] = fmaxf(m0[3], bfhi(v.y));
        m0[4] = fmaxf(m0[4], bflo(v.z)); m0[5] = fmaxf(m0[5], bfhi(v.z));
        m0[6] = fmaxf(m0[6], bflo(v.w)); m0[7] = fmaxf(m0[7], bfhi(v.w));
    }
#pragma unroll
    for (int q = 0; q < 8; q++) m0[q] = fmaxf(fmaxf(m0[q], m1[q]), fmaxf(m2[q], m3[q]));
    uint4 o;  // values are exact bf16 -> pack by truncation
    o.x = (__float_as_uint(m0[0]) >> 16) | (__float_as_uint(m0[1]) & 0xFFFF0000u);
    o.y = (__float_as_uint(m0[2]) >> 16) | (__float_as_uint(m0[3]) & 0xFFFF0000u);
    o.z = (__float_as_uint(m0[4]) >> 16) | (__float_as_uint(m0[5]) & 0xFFFF0000u);
    o.w = (__float_as_uint(m0[6]) >> 16) | (__float_as_uint(m0[7]) & 0xFFFF0000u);
    aggb4[(size_t)node * 16 + j] = o;
}

// ---------------- MFMA GEMM ----------------
// out[row][col] = bias[col] + sum_k A[row][k] * Wcat[col][k]
// A = [srcA | srcB] (TWO_SRC, K=256) or srcA (K=128). 128 rows x 128 cols / block.
template<int NKC16, bool TWO_SRC, bool RELU, bool OUT_BF16>
__global__ __launch_bounds__(256) void mfma_gemm(const u16* __restrict__ srcA,
                                                 const u16* __restrict__ srcB,
                                                 const u16* __restrict__ Bpk,
                                                 const float* __restrict__ bias,
                                                 void* __restrict__ outv) {
    __shared__ s8v ldsB[NKC16 * 4 * 64];
    int tid = threadIdx.x;
#pragma unroll
    for (int i = 0; i < NKC16; i++) {
        ((float4*)ldsB)[tid + 256 * i] = ((const float4*)Bpk)[tid + 256 * i];
    }

    int wt = tid >> 6;
    int lane = tid & 63;
    int row0 = blockIdx.x * 128 + wt * 32;
    int rload = row0 + (lane & 31);
    if (rload > NN - 1) rload = NN - 1;  // clamp OOB loads
    int koff = (lane >> 5) * 8;

    f16v acc[4];
#pragma unroll
    for (int n = 0; n < 4; n++) acc[n] = (f16v)(0.0f);

    __syncthreads();

#pragma unroll
    for (int c = 0; c < NKC16; c++) {
        const u16* s = srcA;
        int kk = c * 16;
        if (TWO_SRC && c >= 8) { s = srcB; kk = (c - 8) * 16; }
        s8v a = *(const s8v*)(s + (size_t)rload * DD + kk + koff);
#pragma unroll
        for (int n = 0; n < 4; n++) {
            s8v b = ldsB[(c * 4 + n) * 64 + lane];
            acc[n] = __builtin_amdgcn_mfma_f32_32x32x16_bf16(a, b, acc[n], 0, 0, 0);
        }
    }

    // epilogue: C/D layout col=lane&31, row=(reg&3)+8*(reg>>2)+4*(lane>>5)
    int rowadd = 4 * (lane >> 5);
#pragma unroll
    for (int n = 0; n < 4; n++) {
        int colj = n * 32 + (lane & 31);
        float bj = bias[colj];
#pragma unroll
        for (int r = 0; r < 16; r++) {
            int row = row0 + (r & 3) + 8 * (r >> 2) + rowadd;
            if (row < NN) {
                float v = acc[n][r] + bj;
                if (RELU) v = fmaxf(v, 0.0f);
                if (OUT_BF16) ((u16*)outv)[(size_t)row * DD + colj] = f2bf(v);
                else          ((float*)outv)[(size_t)row * DD + colj] = v;
            }
        }
    }
}

extern "C" void kernel_launch(void* const* d_in, const int* in_sizes, int n_in,
                              void* d_out, int out_size, void* d_ws, size_t ws_size,
                              hipStream_t stream) {
    const float* x  = (const float*)d_in[0];
    const int*   ei = (const int*)d_in[1];
    const float* Wl = (const float*)d_in[2];
    const float* bl = (const float*)d_in[3];
    const float* Wr = (const float*)d_in[4];
    const float* W  = (const float*)d_in[5];
    const float* b  = (const float*)d_in[6];
    float* out = (float*)d_out;

    // ws layout (16B-aligned chunks)
    u16* aggb = (u16*)d_ws;                         // NN*DD bf16
    u16* hb0  = aggb + (size_t)NN * DD;             // NN*DD
    u16* hb1  = hb0 + (size_t)NN * DD;              // NN*DD
    u16* Bpk0 = hb1 + (size_t)NN * DD;              // 32768
    u16* Bpk1 = Bpk0 + 32768;                       // 32768
    u16* Bpkf = Bpk1 + 32768;                       // 16384
    unsigned* packed = (unsigned*)(Bpkf + 16384);   // NE u32
    int* col    = (int*)(packed + NE);              // NE
    int* rowptr = col + NE;                         // NN+1
    int* bcnt   = rowptr + NN + 1;                  // NBUCK
    int* bbase  = bcnt + NBUCK;                     // NBUCK
    int* bcur   = bbase + NBUCK;                    // NBUCK

    dim3 blk(256);
    int gemmBlocks = (NN + 127) / 128;   // 391
    int aggBlocks  = (NN + 15) / 16;     // 3125
    int convBlocks = (NN * DD / 4 + 255) / 256;

    // CSR build via bucketed counting sort (edge_index identical for both layers)
    zero_int<<<1, blk, 0, stream>>>(bcnt, NBUCK);
    bucket_hist<<<PBLOCKS, blk, 0, stream>>>(ei, bcnt);
    bucket_scan<<<1, blk, 0, stream>>>(bcnt, bbase, bcur, rowptr);
    bucket_partition<<<PBLOCKS, blk, 0, stream>>>(ei, bcur, packed);
    bucket_csr<<<NBUCK, blk, 0, stream>>>(packed, bcnt, bbase, rowptr, col);

    // convert x -> bf16; pack weights into B-fragment order
    conv_bf16<<<convBlocks, blk, 0, stream>>>((const float4*)x, (ushort4*)hb0, NN * DD / 4);
    pack_weights<16, true><<<128, blk, 0, stream>>>(Wl, Wr, Bpk0);
    pack_weights<16, true><<<128, blk, 0, stream>>>(Wl + DD * DD, Wr + DD * DD, Bpk1);
    pack_weights<8, false><<<64, blk, 0, stream>>>(W, nullptr, Bpkf);

    // Layer 0
    agg_kernel_bf<<<aggBlocks, blk, 0, stream>>>((const uint4*)hb0, rowptr, col, (uint4*)aggb);
    mfma_gemm<16, true, true, true><<<gemmBlocks, blk, 0, stream>>>(
        aggb, hb0, Bpk0, bl, hb1);

    // Layer 1
    agg_kernel_bf<<<aggBlocks, blk, 0, stream>>>((const uint4*)hb1, rowptr, col, (uint4*)aggb);
    mfma_gemm<16, true, true, true><<<gemmBlocks, blk, 0, stream>>>(
        aggb, hb1, Bpk1, bl + DD, hb0);

    // Final linear -> fp32 out
    mfma_gemm<8, false, false, false><<<gemmBlocks, blk, 0, stream>>>(
        hb0, nullptr, Bpkf, b, out);
}

// Round 6
// 241.624 us; speedup vs baseline: 4.0106x; 1.0164x over previous
//
#include <hip/hip_runtime.h>
#include <math.h>

#define NN 50000
#define NE 800000
#define DD 128
#define NBUCK 196        // ceil(NN/256) buckets of 256 nodes
#define PTILE 4096       // edges per partition block
#define PBLOCKS 196      // ceil(NE/PTILE)
#define CONVB 6250       // NN*DD/4/256

typedef unsigned short u16;
typedef short s8v __attribute__((ext_vector_type(8)));    // 8 bf16 (4 VGPRs)
typedef float f16v __attribute__((ext_vector_type(16)));  // 16 fp32 acc

__device__ __forceinline__ u16 f2bf(float f) {  // RNE fp32->bf16
    unsigned u = __float_as_uint(f);
    return (u16)((u + 0x7FFFu + ((u >> 16) & 1u)) >> 16);
}
__device__ __forceinline__ float bflo(unsigned u) { return __uint_as_float(u << 16); }
__device__ __forceinline__ float bfhi(unsigned u) { return __uint_as_float(u & 0xFFFF0000u); }

// ---- fused prep: x->bf16 conv | 3x weight pack | zero bcnt ----
// pack order: out[((c*4+n)*64+l)*8+j] = Wcat[col=n*32+(l&31)][k=c*16+(l>>5)*8+j]
__device__ __forceinline__ void pack_one(const float* __restrict__ Wl,
                                         const float* __restrict__ Wr,
                                         bool two, int o, u16* __restrict__ out) {
    int j = o & 7;
    int l = (o >> 3) & 63;
    int cn = o >> 9;
    int n = cn & 3;
    int c = cn >> 2;
    int colj = n * 32 + (l & 31);
    int k = c * 16 + (l >> 5) * 8 + j;
    float v;
    if (two) v = (k < DD) ? Wl[colj * DD + k] : Wr[colj * DD + (k - DD)];
    else     v = Wl[colj * DD + k];
    out[o] = f2bf(v);
}

__global__ __launch_bounds__(256) void prep_kernel(
        const float4* __restrict__ x4, ushort4* __restrict__ hb0,
        const float* __restrict__ Wl, const float* __restrict__ Wr,
        const float* __restrict__ W,
        u16* __restrict__ Bpk0, u16* __restrict__ Bpk1, u16* __restrict__ Bpkf,
        int* __restrict__ bcnt) {
    int bid = blockIdx.x;
    int tid = threadIdx.x;
    if (bid < CONVB) {
        int i = bid * 256 + tid;
        float4 v = x4[i];
        ushort4 o;
        o.x = f2bf(v.x); o.y = f2bf(v.y); o.z = f2bf(v.z); o.w = f2bf(v.w);
        hb0[i] = o;
    } else if (bid < CONVB + 128) {
        pack_one(Wl, Wr, true, (bid - CONVB) * 256 + tid, Bpk0);
    } else if (bid < CONVB + 256) {
        pack_one(Wl + DD * DD, Wr + DD * DD, true, (bid - CONVB - 128) * 256 + tid, Bpk1);
    } else if (bid < CONVB + 320) {
        pack_one(W, W, false, (bid - CONVB - 256) * 256 + tid, Bpkf);
    } else {
        if (tid < NBUCK) bcnt[tid] = 0;
    }
}

// ---- Phase A1: coarse bucket histogram ----
__global__ __launch_bounds__(256) void bucket_hist(const int* __restrict__ ei,
                                                   int* __restrict__ bcnt) {
    __shared__ int h[NBUCK];
    for (int i = threadIdx.x; i < NBUCK; i += 256) h[i] = 0;
    __syncthreads();
    int e0 = blockIdx.x * PTILE;
#pragma unroll
    for (int i = 0; i < 16; i++) {
        int e = e0 + i * 256 + threadIdx.x;
        if (e < NE) atomicAdd(&h[ei[NE + e] >> 8], 1);
    }
    __syncthreads();
    for (int i = threadIdx.x; i < NBUCK; i += 256)
        if (h[i]) atomicAdd(&bcnt[i], h[i]);
}

// ---- Phase A2: scan bucket counts -> bases + cursors ----
__global__ __launch_bounds__(256) void bucket_scan(const int* __restrict__ bcnt,
                                                   int* __restrict__ bbase,
                                                   int* __restrict__ bcur,
                                                   int* __restrict__ rowptr) {
    __shared__ int s[256];
    int t = threadIdx.x;
    int v = (t < NBUCK) ? bcnt[t] : 0;
    s[t] = v;
    __syncthreads();
    for (int o = 1; o < 256; o <<= 1) {
        int u = (t >= o) ? s[t - o] : 0;
        __syncthreads();
        s[t] += u;
        __syncthreads();
    }
    int ex = s[t] - v;
    if (t < NBUCK) { bbase[t] = ex; bcur[t] = ex; }
    if (t == 0) rowptr[NN] = NE;
}

// ---- Phase A3: partition edges into bucket-contiguous packed array ----
__global__ __launch_bounds__(256) void bucket_partition(const int* __restrict__ ei,
                                                        int* __restrict__ bcur,
                                                        unsigned* __restrict__ packed) {
    __shared__ int h[NBUCK];
    __shared__ int base[NBUCK];
    int t = threadIdx.x;
    for (int i = t; i < NBUCK; i += 256) h[i] = 0;
    __syncthreads();
    int e0 = blockIdx.x * PTILE;
    int dsts[16], srcs[16];
#pragma unroll
    for (int i = 0; i < 16; i++) {
        int e = e0 + i * 256 + t;
        if (e < NE) {
            dsts[i] = ei[NE + e];
            srcs[i] = ei[e];
            atomicAdd(&h[dsts[i] >> 8], 1);
        } else dsts[i] = -1;
    }
    __syncthreads();
    for (int i = t; i < NBUCK; i += 256) {
        int c = h[i];
        base[i] = c ? atomicAdd(&bcur[i], c) : 0;
    }
    __syncthreads();
    for (int i = t; i < NBUCK; i += 256) h[i] = 0;  // reuse as local cursor
    __syncthreads();
#pragma unroll
    for (int i = 0; i < 16; i++) {
        if (dsts[i] >= 0) {
            int bk = dsts[i] >> 8;
            int r = atomicAdd(&h[bk], 1);
            packed[base[bk] + r] = (unsigned)srcs[i] | ((unsigned)(dsts[i] & 255) << 16);
        }
    }
}

// ---- Phase B: per-bucket counting sort -> rowptr + col ----
__global__ __launch_bounds__(256) void bucket_csr(const unsigned* __restrict__ packed,
                                                  const int* __restrict__ bcnt,
                                                  const int* __restrict__ bbase,
                                                  int* __restrict__ rowptr,
                                                  int* __restrict__ col) {
    __shared__ int deg[256];
    __shared__ int off[256];
    int bk = blockIdx.x;
    int cnt = bcnt[bk], base = bbase[bk];
    int t = threadIdx.x;
    deg[t] = 0;
    __syncthreads();
    for (int i = t; i < cnt; i += 256) atomicAdd(&deg[packed[base + i] >> 16], 1);
    __syncthreads();
    int v = deg[t];
    off[t] = v;
    __syncthreads();
    for (int o = 1; o < 256; o <<= 1) {
        int u = (t >= o) ? off[t - o] : 0;
        __syncthreads();
        off[t] += u;
        __syncthreads();
    }
    int ex = off[t] - v;
    int node = (bk << 8) + t;
    if (node < NN) rowptr[node] = base + ex;
    deg[t] = ex;  // reuse as cursor
    __syncthreads();
    for (int i = t; i < cnt; i += 256) {
        unsigned p = packed[base + i];
        int dl = p >> 16;
        int r = atomicAdd(&deg[dl], 1);
        col[base + r] = (int)(p & 0xFFFFu);
    }
}

// ---- segmented max on bf16 (CSR), 16 lanes/node, 16B/lane, unroll-8 ----
__device__ __forceinline__ void vmax8(float* m, uint4 v) {
    m[0] = fmaxf(m[0], bflo(v.x)); m[1] = fmaxf(m[1], bfhi(v.x));
    m[2] = fmaxf(m[2], bflo(v.y)); m[3] = fmaxf(m[3], bfhi(v.y));
    m[4] = fmaxf(m[4], bflo(v.z)); m[5] = fmaxf(m[5], bfhi(v.z));
    m[6] = fmaxf(m[6], bflo(v.w)); m[7] = fmaxf(m[7], bfhi(v.w));
}

__global__ __launch_bounds__(256) void agg_kernel_bf(const uint4* __restrict__ xb4,
                                                     const int* __restrict__ row_ptr,
                                                     const int* __restrict__ col,
                                                     uint4* __restrict__ aggb4) {
    int node = blockIdx.x * 16 + (threadIdx.x >> 4);
    if (node >= NN) return;
    int j = threadIdx.x & 15;
    int s0 = row_ptr[node], s1 = row_ptr[node + 1];
    if (s0 == s1) {
        aggb4[(size_t)node * 16 + j] = make_uint4(0, 0, 0, 0);
        return;
    }
    float m0[8], m1[8], m2[8], m3[8];
#pragma unroll
    for (int q = 0; q < 8; q++) { m0[q] = m1[q] = m2[q] = m3[q] = -INFINITY; }
    int i = s0;
    for (; i + 8 <= s1; i += 8) {
        int c0 = col[i],     c1 = col[i + 1], c2 = col[i + 2], c3 = col[i + 3];
        int c4 = col[i + 4], c5 = col[i + 5], c6 = col[i + 6], c7 = col[i + 7];
        uint4 v0 = xb4[(size_t)c0 * 16 + j];
        uint4 v1 = xb4[(size_t)c1 * 16 + j];
        uint4 v2 = xb4[(size_t)c2 * 16 + j];
        uint4 v3 = xb4[(size_t)c3 * 16 + j];
        uint4 v4 = xb4[(size_t)c4 * 16 + j];
        uint4 v5 = xb4[(size_t)c5 * 16 + j];
        uint4 v6 = xb4[(size_t)c6 * 16 + j];
        uint4 v7 = xb4[(size_t)c7 * 16 + j];
        vmax8(m0, v0); vmax8(m1, v1); vmax8(m2, v2); vmax8(m3, v3);
        vmax8(m0, v4); vmax8(m1, v5); vmax8(m2, v6); vmax8(m3, v7);
    }
    for (; i + 4 <= s1; i += 4) {
        int c0 = col[i], c1 = col[i + 1], c2 = col[i + 2], c3 = col[i + 3];
        uint4 v0 = xb4[(size_t)c0 * 16 + j];
        uint4 v1 = xb4[(size_t)c1 * 16 + j];
        uint4 v2 = xb4[(size_t)c2 * 16 + j];
        uint4 v3 = xb4[(size_t)c3 * 16 + j];
        vmax8(m0, v0); vmax8(m1, v1); vmax8(m2, v2); vmax8(m3, v3);
    }
    for (; i < s1; i++) {
        uint4 v = xb4[(size_t)col[i] * 16 + j];
        vmax8(m0, v);
    }
#pragma unroll
    for (int q = 0; q < 8; q++) m0[q] = fmaxf(fmaxf(m0[q], m1[q]), fmaxf(m2[q], m3[q]));
    uint4 o;  // values are exact bf16 -> pack by truncation
    o.x = (__float_as_uint(m0[0]) >> 16) | (__float_as_uint(m0[1]) & 0xFFFF0000u);
    o.y = (__float_as_uint(m0[2]) >> 16) | (__float_as_uint(m0[3]) & 0xFFFF0000u);
    o.z = (__float_as_uint(m0[4]) >> 16) | (__float_as_uint(m0[5]) & 0xFFFF0000u);
    o.w = (__float_as_uint(m0[6]) >> 16) | (__float_as_uint(m0[7]) & 0xFFFF0000u);
    aggb4[(size_t)node * 16 + j] = o;
}

// ---------------- MFMA GEMM (no LDS: B-fragments straight from L2) ----------------
// out[row][col] = bias[col] + sum_k A[row][k] * Wcat[col][k]
// A = [srcA | srcB] (TWO_SRC, K=256) or srcA (K=128). 128 rows x 128 cols / block.
template<int NKC16, bool TWO_SRC, bool RELU, bool OUT_BF16>
__global__ __launch_bounds__(256) void mfma_gemm(const u16* __restrict__ srcA,
                                                 const u16* __restrict__ srcB,
                                                 const u16* __restrict__ Bpk,
                                                 const float* __restrict__ bias,
                                                 void* __restrict__ outv) {
    int tid = threadIdx.x;
    int wt = tid >> 6;
    int lane = tid & 63;
    int row0 = blockIdx.x * 128 + wt * 32;
    int rload = row0 + (lane & 31);
    if (rload > NN - 1) rload = NN - 1;  // clamp OOB loads
    int koff = (lane >> 5) * 8;
    const s8v* Bv = (const s8v*)Bpk;

    f16v acc[4];
#pragma unroll
    for (int n = 0; n < 4; n++) acc[n] = (f16v)(0.0f);

#pragma unroll
    for (int c = 0; c < NKC16; c++) {
        const u16* s = srcA;
        int kk = c * 16;
        if (TWO_SRC && c >= 8) { s = srcB; kk = (c - 8) * 16; }
        s8v a = *(const s8v*)(s + (size_t)rload * DD + kk + koff);
#pragma unroll
        for (int n = 0; n < 4; n++) {
            s8v b = Bv[(c * 4 + n) * 64 + lane];
            acc[n] = __builtin_amdgcn_mfma_f32_32x32x16_bf16(a, b, acc[n], 0, 0, 0);
        }
    }

    // epilogue: C/D layout col=lane&31, row=(reg&3)+8*(reg>>2)+4*(lane>>5)
    int rowadd = 4 * (lane >> 5);
#pragma unroll
    for (int n = 0; n < 4; n++) {
        int colj = n * 32 + (lane & 31);
        float bj = bias[colj];
#pragma unroll
        for (int r = 0; r < 16; r++) {
            int row = row0 + (r & 3) + 8 * (r >> 2) + rowadd;
            if (row < NN) {
                float v = acc[n][r] + bj;
                if (RELU) v = fmaxf(v, 0.0f);
                if (OUT_BF16) ((u16*)outv)[(size_t)row * DD + colj] = f2bf(v);
                else          ((float*)outv)[(size_t)row * DD + colj] = v;
            }
        }
    }
}

extern "C" void kernel_launch(void* const* d_in, const int* in_sizes, int n_in,
                              void* d_out, int out_size, void* d_ws, size_t ws_size,
                              hipStream_t stream) {
    const float* x  = (const float*)d_in[0];
    const int*   ei = (const int*)d_in[1];
    const float* Wl = (const float*)d_in[2];
    const float* bl = (const float*)d_in[3];
    const float* Wr = (const float*)d_in[4];
    const float* W  = (const float*)d_in[5];
    const float* b  = (const float*)d_in[6];
    float* out = (float*)d_out;

    // ws layout (16B-aligned chunks)
    u16* aggb = (u16*)d_ws;                         // NN*DD bf16
    u16* hb0  = aggb + (size_t)NN * DD;             // NN*DD
    u16* hb1  = hb0 + (size_t)NN * DD;              // NN*DD
    u16* Bpk0 = hb1 + (size_t)NN * DD;              // 32768
    u16* Bpk1 = Bpk0 + 32768;                       // 32768
    u16* Bpkf = Bpk1 + 32768;                       // 16384
    unsigned* packed = (unsigned*)(Bpkf + 16384);   // NE u32
    int* col    = (int*)(packed + NE);              // NE
    int* rowptr = col + NE;                         // NN+1
    int* bcnt   = rowptr + NN + 1;                  // NBUCK
    int* bbase  = bcnt + NBUCK;                     // NBUCK
    int* bcur   = bbase + NBUCK;                    // NBUCK

    dim3 blk(256);
    int gemmBlocks = (NN + 127) / 128;   // 391
    int aggBlocks  = (NN + 15) / 16;     // 3125
    int prepBlocks = CONVB + 320 + 1;    // conv + pack0 + pack1 + packf + zero

    // fused prep (conv + weight packs + bcnt zero)
    prep_kernel<<<prepBlocks, blk, 0, stream>>>(
        (const float4*)x, (ushort4*)hb0, Wl, Wr, W, Bpk0, Bpk1, Bpkf, bcnt);

    // CSR build via bucketed counting sort
    bucket_hist<<<PBLOCKS, blk, 0, stream>>>(ei, bcnt);
    bucket_scan<<<1, blk, 0, stream>>>(bcnt, bbase, bcur, rowptr);
    bucket_partition<<<PBLOCKS, blk, 0, stream>>>(ei, bcur, packed);
    bucket_csr<<<NBUCK, blk, 0, stream>>>(packed, bcnt, bbase, rowptr, col);

    // Layer 0
    agg_kernel_bf<<<aggBlocks, blk, 0, stream>>>((const uint4*)hb0, rowptr, col, (uint4*)aggb);
    mfma_gemm<16, true, true, true><<<gemmBlocks, blk, 0, stream>>>(
        aggb, hb0, Bpk0, bl, hb1);

    // Layer 1
    agg_kernel_bf<<<aggBlocks, blk, 0, stream>>>((const uint4*)hb1, rowptr, col, (uint4*)aggb);
    mfma_gemm<16, true, true, true><<<gemmBlocks, blk, 0, stream>>>(
        aggb, hb1, Bpk1, bl + DD, hb0);

    // Final linear -> fp32 out
    mfma_gemm<8, false, false, false><<<gemmBlocks, blk, 0, stream>>>(
        hb0, nullptr, Bpkf, b, out);
}